// Round 4
// baseline (1382.978 us; speedup 1.0000x reference)
//
#include <hip/hip_runtime.h>

#define BB 4
#define CC 1024
#define TT 1024
#define HH 16
#define DD 64

typedef __bf16 v8bf __attribute__((ext_vector_type(8)));
typedef __bf16 v4bf __attribute__((ext_vector_type(4)));
typedef float  v4f  __attribute__((ext_vector_type(4)));

// async global->LDS, 16B per lane. LDS dest must be wave-uniform base (HW writes
// base + lane*16); global src is per-lane.
__device__ __forceinline__ void async16(const __bf16* g, __bf16* l) {
  __builtin_amdgcn_global_load_lds(
      (const __attribute__((address_space(1))) void*)g,
      (__attribute__((address_space(3))) void*)l, 16, 0, 0);
}

// ---- prep: mask detection+expand+bitpack | weight casts | transpose_x ------
__global__ __launch_bounds__(256) void prep(
    const void* mraw, float* __restrict__ maskf, unsigned int* __restrict__ kmb,
    const float* __restrict__ w_kvq, const float* __restrict__ w_out,
    __bf16* __restrict__ wkb, __bf16* __restrict__ wob,
    const float* __restrict__ x, __bf16* __restrict__ xT)
{
  const int blk = blockIdx.x;
  const int tid = threadIdx.x;
  __shared__ int flagA, flagB;
  __shared__ __bf16 T[64][72];

  if (blk == 0) {
    if (tid == 0) { flagA = 0; flagB = 0; }
    __syncthreads();
    const unsigned char* mb = (const unsigned char*)mraw;
    const int n = BB * TT;
    int a = 0, bfl = 0;
    for (int i = tid; i < n; i += 256) {
      if (mb[i]) { if ((i & 3) == 0) a = 1; else bfl = 1; }
    }
    if (a)   atomicOr(&flagA, 1);
    if (bfl) atomicOr(&flagB, 1);
    __syncthreads();
    int layout;                         // 0=int32, 1=float32, 2=uint8
    if (flagA && !flagB)      layout = 0;
    else if (!flagA && flagB) layout = 1;
    else                      layout = 2;
    const int lane = tid & 63, wave = tid >> 6;
    for (int it = 0; it < 16; it++) {
      int i = it * 256 + tid;
      float m;
      if (layout == 0)      m = (((const int*)mraw)[i]   != 0)   ? 1.f : 0.f;
      else if (layout == 1) m = (((const float*)mraw)[i] != 0.f) ? 1.f : 0.f;
      else                  m = (mb[i] != 0)                     ? 1.f : 0.f;
      maskf[i] = m;
      unsigned long long bal = __ballot(m != 0.f);
      if (lane == 0) {
        int base = (it * 256 + wave * 64) >> 5;
        kmb[base]     = (unsigned int)bal;
        kmb[base + 1] = (unsigned int)(bal >> 32);
      }
    }
  } else if (blk <= 2048) {
    const int cb = blk - 1;
    const float* src; __bf16* dst; int base;
    if (cb < 1536) { src = w_kvq; dst = wkb; base = cb * 2048; }
    else           { src = w_out; dst = wob; base = (cb - 1536) * 2048; }
    int i = base + tid * 8;
    float4 f0 = *(const float4*)(src + i);
    float4 f1 = *(const float4*)(src + i + 4);
    v8bf o;
    o[0] = (__bf16)f0.x; o[1] = (__bf16)f0.y; o[2] = (__bf16)f0.z; o[3] = (__bf16)f0.w;
    o[4] = (__bf16)f1.x; o[5] = (__bf16)f1.y; o[6] = (__bf16)f1.z; o[7] = (__bf16)f1.w;
    *(v8bf*)(dst + i) = o;
  } else {
    const int idx = blk - 2049;                 // [0,1024)
    const int t0 = (idx & 15) * 64, c0 = ((idx >> 4) & 15) * 64, b = idx >> 8;
    {
      int row = tid >> 2, coff = (tid & 3) * 16;
      const float* src = x + ((long)b * CC + c0 + row) * TT + t0 + coff;
#pragma unroll
      for (int s = 0; s < 4; s++) {
        float4 f = *(const float4*)(src + s * 4);
        T[row][coff + s * 4 + 0] = (__bf16)f.x;
        T[row][coff + s * 4 + 1] = (__bf16)f.y;
        T[row][coff + s * 4 + 2] = (__bf16)f.z;
        T[row][coff + s * 4 + 3] = (__bf16)f.w;
      }
    }
    __syncthreads();
    {
      int trow = tid >> 2, ccoff = (tid & 3) * 16;
      __bf16 vals[16];
#pragma unroll
      for (int i = 0; i < 16; i++) vals[i] = T[ccoff + i][trow];
      __bf16* dst = xT + ((long)b * TT + t0 + trow) * CC + c0 + ccoff;
      *(v8bf*)dst       = *(v8bf*)&vals[0];
      *(v8bf*)(dst + 8) = *(v8bf*)&vals[8];
    }
  }
}

// ------- kvq [b][3C][T] bf16 -> kqT [b][t][2C]: [t][c]=k, [t][C+c]=q -------
__global__ __launch_bounds__(256) void transpose_kq(const __bf16* __restrict__ kvqb,
                                                    __bf16* __restrict__ kqT) {
  const int zz = blockIdx.z;
  const int b = zz >> 1, part = zz & 1;
  const int srcbase = part == 0 ? 0 : 2 * CC;
  const int dstbase = part * CC;
  const int t0 = blockIdx.x * 64, c0 = blockIdx.y * 64;
  __shared__ __bf16 T[64][72];
  const int tid = threadIdx.x;
  {
    int row = tid >> 2, coff = (tid & 3) * 16;
    const __bf16* src = kvqb + ((long)b * 3 * CC + srcbase + c0 + row) * TT + t0 + coff;
    *(v8bf*)&T[row][coff]     = *(const v8bf*)src;
    *(v8bf*)&T[row][coff + 8] = *(const v8bf*)(src + 8);
  }
  __syncthreads();
  {
    int trow = tid >> 2, ccoff = (tid & 3) * 16;
    __bf16 vals[16];
#pragma unroll
    for (int i = 0; i < 16; i++) vals[i] = T[ccoff + i][trow];
    __bf16* dst = kqT + ((long)b * TT + t0 + trow) * (2 * CC) + dstbase + c0 + ccoff;
    *(v8bf*)dst       = *(v8bf*)&vals[0];
    *(v8bf*)(dst + 8) = *(v8bf*)&vals[8];
  }
}

// ------- MFMA GEMM: C[m][n] = sum_k A[m][k]*BT[n][k]  (K=1024 fixed) -------
// RPT: instrumentation repeat (identical recompute; acc re-zeroed per pass).
template <int MODE, int NB, int MB, int RPT>
__global__ __launch_bounds__(256) void gemm_bt(
    const __bf16* __restrict__ A, const __bf16* __restrict__ BTfull,
    const float* __restrict__ Sfull, void* __restrict__ Ofull,
    long strideBT, long strideOS)
{
  constexpr int TOT = NB * MB * BB;
  int flat = blockIdx.x + NB * (blockIdx.y + MB * blockIdx.z);
  int L = (flat & 7) * (TOT / 8) + (flat >> 3);
  const int n0 = (L % NB) * 128;
  const int m0 = ((L / NB) % MB) * 128;
  const int zb = L / (NB * MB);
  const __bf16* BT = BTfull + (long)zb * strideBT;
  __shared__ __align__(16) __bf16 As[128 * 32];
  __shared__ __align__(16) __bf16 Bs[128 * 32];
  const int tid = threadIdx.x;
  const int lane = tid & 63, wave = tid >> 6;
  const int wm = wave >> 1, wn = wave & 1;
  const int ln = lane & 15, q = lane >> 4;

  const int e0 = tid * 8;
  const int r0 = e0 >> 5, c0 = e0 & 31;
  const int e1 = (256 + tid) * 8;
  const int r1 = e1 >> 5, c1 = e1 & 31;
  const __bf16* ga0 = A  + (long)(m0 + r0) * CC + c0;
  const __bf16* ga1 = A  + (long)(m0 + r1) * CC + c1;
  const __bf16* gb0 = BT + (long)(n0 + r0) * CC + c0;
  const __bf16* gb1 = BT + (long)(n0 + r1) * CC + c1;
  __bf16* lA0 = &As[wave * 512];
  __bf16* lA1 = &As[2048 + wave * 512];
  __bf16* lB0 = &Bs[wave * 512];
  __bf16* lB1 = &Bs[2048 + wave * 512];

  v4f acc[4][4];
  for (int rp = 0; rp < RPT; ++rp) {
#pragma unroll
    for (int i = 0; i < 4; i++)
#pragma unroll
      for (int j = 0; j < 4; j++) acc[i][j] = (v4f)(0.f);

    for (int k0 = 0; k0 < CC; k0 += 32) {
      async16(ga0 + k0, lA0);
      async16(ga1 + k0, lA1);
      async16(gb0 + k0, lB0);
      async16(gb1 + k0, lB1);
      __syncthreads();
      v8bf af[4], bfr[4];
#pragma unroll
      for (int mi = 0; mi < 4; mi++)
        af[mi] = *(v8bf*)&As[(wm * 64 + mi * 16 + ln) * 32 + q * 8];
#pragma unroll
      for (int ni = 0; ni < 4; ni++)
        bfr[ni] = *(v8bf*)&Bs[(wn * 64 + ni * 16 + ln) * 32 + q * 8];
#pragma unroll
      for (int mi = 0; mi < 4; mi++)
#pragma unroll
        for (int ni = 0; ni < 4; ni++)
          acc[mi][ni] = __builtin_amdgcn_mfma_f32_16x16x32_bf16(af[mi], bfr[ni], acc[mi][ni], 0, 0, 0);
      __syncthreads();
    }
  }
#pragma unroll
  for (int mi = 0; mi < 4; mi++)
#pragma unroll
    for (int ni = 0; ni < 4; ni++)
#pragma unroll
      for (int r = 0; r < 4; r++) {
        int row = m0 + wm * 64 + mi * 16 + q * 4 + r;
        int col = n0 + wn * 64 + ni * 16 + ln;
        if (MODE == 0) {
          ((__bf16*)Ofull)[(long)zb * strideOS + (long)row * TT + col] = (__bf16)acc[mi][ni][r];
        } else {
          long off = (long)zb * strideOS + (long)row * TT + col;
          ((float*)Ofull)[off] = acc[mi][ni][r] + Sfull[off];
        }
      }
}

// ------- stats: per (z, i-chunk 64, j) partial sumexp of logits ------------
__global__ __launch_bounds__(256) void attn_stats(
    const __bf16* __restrict__ kqT, const float* __restrict__ maskf,
    float* __restrict__ psum)
{
  int L = blockIdx.x + 8 * (blockIdx.y + 8 * blockIdx.z);
  L = (L & 7) * 512 + (L >> 3);                  // XCD chunk (4096 = 8*512)
  const int jx = L & 7, iy = (L >> 3) & 7, z = L >> 6;
  const int h = z >> 2, b = z & 3;
  const int i0 = iy * 128, j0 = jx * 128;
  const __bf16* kbase = kqT + (long)b * TT * (2 * CC);
  const int tid = threadIdx.x;
  const int lane = tid & 63, wave = tid >> 6;
  const int wi = wave >> 1, wj = wave & 1;
  const int ln = lane & 15, q = lane >> 4;

  for (int rp = 0; rp < 16; ++rp) {              // instrumentation repeat
    v8bf ak[4][2], bq[4][2];
#pragma unroll
    for (int mi = 0; mi < 4; mi++) {
      const __bf16* ar = kbase + (long)(i0 + wi * 64 + mi * 16 + ln) * (2 * CC) + h * DD;
      ak[mi][0] = *(const v8bf*)(ar + q * 8);
      ak[mi][1] = *(const v8bf*)(ar + 32 + q * 8);
    }
#pragma unroll
    for (int ni = 0; ni < 4; ni++) {
      const __bf16* br = kbase + (long)(j0 + wj * 64 + ni * 16 + ln) * (2 * CC) + CC + h * DD;
      bq[ni][0] = *(const v8bf*)(br + q * 8);
      bq[ni][1] = *(const v8bf*)(br + 32 + q * 8);
    }

    v4f acc[4][4];
    __builtin_amdgcn_s_setprio(1);
#pragma unroll
    for (int mi = 0; mi < 4; mi++)
#pragma unroll
      for (int ni = 0; ni < 4; ni++) {
        v4f a = (v4f)(0.f);
        a = __builtin_amdgcn_mfma_f32_16x16x32_bf16(ak[mi][0], bq[ni][0], a, 0, 0, 0);
        a = __builtin_amdgcn_mfma_f32_16x16x32_bf16(ak[mi][1], bq[ni][1], a, 0, 0, 0);
        acc[mi][ni] = a;
      }
    __builtin_amdgcn_s_setprio(0);

    float kmv[4][4];
#pragma unroll
    for (int mi = 0; mi < 4; mi++)
#pragma unroll
      for (int r = 0; r < 4; r++)
        kmv[mi][r] = maskf[b * TT + i0 + wi * 64 + mi * 16 + q * 4 + r];

#pragma unroll
    for (int ni = 0; ni < 4; ni++) {
      float s = 0.f;
#pragma unroll
      for (int mi = 0; mi < 4; mi++)
#pragma unroll
        for (int r = 0; r < 4; r++) {
          float e = (kmv[mi][r] != 0.f) ? 0.f : __expf(acc[mi][ni][r] * 0.125f);
          s += e;
        }
      s += __shfl_xor(s, 16, 64);
      s += __shfl_xor(s, 32, 64);
      if (q == 0) {
        long so = ((long)z * 16 + (i0 >> 6) + wi) * TT + j0 + wj * 64 + ni * 16 + ln;
        psum[so] = s;
      }
    }
  }
}

// ------- recompute logits, p=exp(l)*qz/S -> att; o^T = p^T v^T -------------
__global__ __launch_bounds__(256) void gemm_pv(
    const __bf16* __restrict__ kqT, const __bf16* __restrict__ kvqb,
    const float* __restrict__ psum, const float* __restrict__ maskf,
    const unsigned int* __restrict__ kmb,
    float* __restrict__ att, __bf16* __restrict__ oT)
{
  int L = blockIdx.x + 16 * blockIdx.y;
  L = (L & 7) * 128 + (L >> 3);                 // XCD chunk (1024 = 8*128)
  const int z = L >> 4, jb = L & 15;
  const int h = z >> 2, b = z & 3;
  const int j0 = jb * 64;
  __shared__ __align__(16) char smem[37376];
  float* stl = (float*)smem;                    // [64] f32 @0
  unsigned int* kmw = (unsigned int*)(smem + 256);  // [32] u32 @256
  const int tid = threadIdx.x;
  const int lane = tid & 63, wave = tid >> 6;
  const int ln = lane & 15, q = lane >> 4;
  __bf16 (*Pt)[72] = (__bf16(*)[72])(smem + 512 + wave * 9216); // per-wave 64x72

  const __bf16* kbase = kqT + (long)b * TT * (2 * CC);
  const __bf16* vbase = kvqb + (long)(b * 3 * CC + CC + h * DD) * TT;

  if (tid < 64) {
    float S = 0.f;
#pragma unroll
    for (int t = 0; t < 16; t++) S += psum[((long)z * 16 + t) * TT + j0 + tid];
    stl[tid] = (maskf[b * TT + j0 + tid] != 0.f) ? 0.f : 1.f / S;
  }
  if (tid < 32) kmw[tid] = kmb[b * 32 + tid];
  __syncthreads();

  v8bf bq[4][2];
#pragma unroll
  for (int ni = 0; ni < 4; ni++) {
    const __bf16* qr = kbase + (long)(j0 + ni * 16 + ln) * (2 * CC) + CC + h * DD;
    bq[ni][0] = *(const v8bf*)(qr + q * 8);
    bq[ni][1] = *(const v8bf*)(qr + 32 + q * 8);
  }
  float stq[4];
#pragma unroll
  for (int ni = 0; ni < 4; ni++) stq[ni] = stl[ni * 16 + ln];

  v4f acc[4][4];
  for (int rp = 0; rp < 6; ++rp) {              // instrumentation repeat
#pragma unroll
    for (int i = 0; i < 4; i++)
#pragma unroll
      for (int j = 0; j < 4; j++) acc[i][j] = (v4f)(0.f);

    for (int it = 0; it < 4; it++) {
      const int ibase = wave * 256 + it * 64;
#pragma unroll
      for (int mi = 0; mi < 4; mi++) {
        const __bf16* arow = kbase + (long)(ibase + mi * 16 + ln) * (2 * CC) + h * DD;
        v8bf ak0 = *(const v8bf*)(arow + q * 8);
        v8bf ak1 = *(const v8bf*)(arow + 32 + q * 8);
#pragma unroll
        for (int ni = 0; ni < 4; ni++) {
          v4f l4 = (v4f)(0.f);
          l4 = __builtin_amdgcn_mfma_f32_16x16x32_bf16(ak0, bq[ni][0], l4, 0, 0, 0);
          l4 = __builtin_amdgcn_mfma_f32_16x16x32_bf16(ak1, bq[ni][1], l4, 0, 0, 0);
          v4bf pb;
#pragma unroll
          for (int r = 0; r < 4; r++) {
            int i_loc = mi * 16 + q * 4 + r;
            int i_glob = ibase + i_loc;
            unsigned int mbit = (kmw[i_glob >> 5] >> (i_glob & 31)) & 1u;
            float p = mbit ? 0.f : __expf(l4[r] * 0.125f) * stq[ni];
            att[((long)z << 20) + (long)i_glob * TT + j0 + ni * 16 + ln] = p;
            pb[r] = (__bf16)p;
          }
          *(v4bf*)&Pt[ni * 16 + ln][mi * 16 + q * 4] = pb;
        }
      }
      v8bf ap[4][2], bv[4][2];
#pragma unroll
      for (int ji = 0; ji < 4; ji++)
#pragma unroll
        for (int ki = 0; ki < 2; ki++)
          ap[ji][ki] = *(v8bf*)&Pt[ji * 16 + ln][ki * 32 + q * 8];
#pragma unroll
      for (int di = 0; di < 4; di++)
#pragma unroll
        for (int ki = 0; ki < 2; ki++)
          bv[di][ki] = *(const v8bf*)(vbase + (long)(di * 16 + ln) * TT + ibase + ki * 32 + q * 8);
      __builtin_amdgcn_s_setprio(1);
#pragma unroll
      for (int ji = 0; ji < 4; ji++)
#pragma unroll
        for (int di = 0; di < 4; di++) {
          acc[ji][di] = __builtin_amdgcn_mfma_f32_16x16x32_bf16(ap[ji][0], bv[di][0], acc[ji][di], 0, 0, 0);
          acc[ji][di] = __builtin_amdgcn_mfma_f32_16x16x32_bf16(ap[ji][1], bv[di][1], acc[ji][di], 0, 0, 0);
        }
      __builtin_amdgcn_s_setprio(0);
    }
  }

  float (*red0)[68] = (float(*)[68])(smem + 512);
  float (*red1)[68] = (float(*)[68])(smem + 512 + 17408);
  __syncthreads();
  if ((wave & 1) == 0) {
    float (*red)[68] = (wave == 0) ? red0 : red1;
#pragma unroll
    for (int ji = 0; ji < 4; ji++)
#pragma unroll
      for (int di = 0; di < 4; di++)
#pragma unroll
        for (int r = 0; r < 4; r++)
          red[ji * 16 + q * 4 + r][di * 16 + ln] = acc[ji][di][r];
  }
  __syncthreads();
  if ((wave & 1) == 1) {
    float (*red)[68] = (wave == 1) ? red0 : red1;
#pragma unroll
    for (int ji = 0; ji < 4; ji++)
#pragma unroll
      for (int di = 0; di < 4; di++)
#pragma unroll
        for (int r = 0; r < 4; r++)
          red[ji * 16 + q * 4 + r][di * 16 + ln] += acc[ji][di][r];
  }
  __syncthreads();
  {
    int row = tid >> 2, c0 = (tid & 3) * 16;
    __bf16 ob[16];
#pragma unroll
    for (int i = 0; i < 16; i++) ob[i] = (__bf16)(red0[row][c0 + i] + red1[row][c0 + i]);
    __bf16* dst = oT + ((long)b * TT + j0 + row) * CC + h * DD + c0;
    *(v8bf*)dst       = *(v8bf*)&ob[0];
    *(v8bf*)(dst + 8) = *(v8bf*)&ob[8];
  }
}

extern "C" void kernel_launch(void* const* d_in, const int* in_sizes, int n_in,
                              void* d_out, int out_size, void* d_ws, size_t ws_size,
                              hipStream_t stream) {
  const float* x     = (const float*)d_in[0];
  const void*  mask  = d_in[1];
  const float* w_kvq = (const float*)d_in[2];
  const float* w_out = (const float*)d_in[3];

  float* out = (float*)d_out;                     // [BB, CC, TT]
  float* att = out + (long)BB * CC * TT;          // [HH*BB, TT, TT]

  char* wsb = (char*)d_ws;
  float*   maskf = (float*)(wsb + 0);             // 16 KB
  __bf16*  wkb   = (__bf16*)(wsb + 16384);        // 6 MB
  __bf16*  wob   = (__bf16*)(wsb + 6307840);      // 2 MB
  __bf16*  xT    = (__bf16*)(wsb + 8404992);      // 8 MB   (region R)
  __bf16*  kqT   = (__bf16*)(wsb + 8404992);      // 16 MB  (region R, after xT dead)
  __bf16*  kvqb  = (__bf16*)(wsb + 25182208);     // 24 MB
  __bf16*  oT    = (__bf16*)(wsb + 50348032);     // 8 MB
  float*   psum  = (float*)(wsb + 58736640);      // 4 MB, ends 62930944
  unsigned int* kmb = (unsigned int*)(wsb + 62930944); // 512 B (within proven 67.6MB)

  prep<<<3073, 256, 0, stream>>>(mask, maskf, kmb, w_kvq, w_out, wkb, wob, x, xT);
  // kvq[m][n] = sum_k w_kvq[m][k] x[k][n]   (instrumented x8)
  gemm_bt<0, 8, 24, 8><<<dim3(8, 24, BB), 256, 0, stream>>>(
      wkb, xT, nullptr, kvqb, (long)CC * TT, (long)3 * CC * TT);
  transpose_kq<<<dim3(16, 16, 2 * BB), 256, 0, stream>>>(kvqb, kqT);
  attn_stats<<<dim3(8, 8, HH * BB), 256, 0, stream>>>(kqT, maskf, psum);        // x16
  gemm_pv<<<dim3(16, HH * BB), 256, 0, stream>>>(kqT, kvqb, psum, maskf, kmb, att, oT); // x6
  // out = x + w_out · o   (instrumented x10)
  gemm_bt<1, 8, 8, 10><<<dim3(8, 8, BB), 256, 0, stream>>>(
      wob, oT, x, out, (long)CC * TT, (long)CC * TT);
}

// Round 5
// 607.260 us; speedup vs baseline: 2.2774x; 2.2774x over previous
//
#include <hip/hip_runtime.h>

#define BB 4
#define CC 1024
#define TT 1024
#define HH 16
#define DD 64

typedef __bf16 v8bf __attribute__((ext_vector_type(8)));
typedef __bf16 v4bf __attribute__((ext_vector_type(4)));
typedef float  v4f  __attribute__((ext_vector_type(4)));

// async global->LDS, 16B per lane. LDS dest must be wave-uniform base (HW writes
// base + lane*16); global src is per-lane.
__device__ __forceinline__ void async16(const __bf16* g, __bf16* l) {
  __builtin_amdgcn_global_load_lds(
      (const __attribute__((address_space(1))) void*)g,
      (__attribute__((address_space(3))) void*)l, 16, 0, 0);
}

// ---- prep: mask detection+expand+bitpack | weight casts | transpose_x ------
__global__ __launch_bounds__(256) void prep(
    const void* mraw, float* __restrict__ maskf, unsigned int* __restrict__ kmb,
    const float* __restrict__ w_kvq, const float* __restrict__ w_out,
    __bf16* __restrict__ wkb, __bf16* __restrict__ wob,
    const float* __restrict__ x, __bf16* __restrict__ xT)
{
  const int blk = blockIdx.x;
  const int tid = threadIdx.x;
  __shared__ int flagA, flagB;
  __shared__ __bf16 T[64][72];

  if (blk == 0) {
    if (tid == 0) { flagA = 0; flagB = 0; }
    __syncthreads();
    const unsigned char* mb = (const unsigned char*)mraw;
    const int n = BB * TT;
    int a = 0, bfl = 0;
    for (int i = tid; i < n; i += 256) {
      if (mb[i]) { if ((i & 3) == 0) a = 1; else bfl = 1; }
    }
    if (a)   atomicOr(&flagA, 1);
    if (bfl) atomicOr(&flagB, 1);
    __syncthreads();
    int layout;                         // 0=int32, 1=float32, 2=uint8
    if (flagA && !flagB)      layout = 0;
    else if (!flagA && flagB) layout = 1;
    else                      layout = 2;
    const int lane = tid & 63, wave = tid >> 6;
    for (int it = 0; it < 16; it++) {
      int i = it * 256 + tid;
      float m;
      if (layout == 0)      m = (((const int*)mraw)[i]   != 0)   ? 1.f : 0.f;
      else if (layout == 1) m = (((const float*)mraw)[i] != 0.f) ? 1.f : 0.f;
      else                  m = (mb[i] != 0)                     ? 1.f : 0.f;
      maskf[i] = m;
      unsigned long long bal = __ballot(m != 0.f);
      if (lane == 0) {
        int base = (it * 256 + wave * 64) >> 5;
        kmb[base]     = (unsigned int)bal;
        kmb[base + 1] = (unsigned int)(bal >> 32);
      }
    }
  } else if (blk <= 2048) {
    const int cb = blk - 1;
    const float* src; __bf16* dst; int base;
    if (cb < 1536) { src = w_kvq; dst = wkb; base = cb * 2048; }
    else           { src = w_out; dst = wob; base = (cb - 1536) * 2048; }
    int i = base + tid * 8;
    float4 f0 = *(const float4*)(src + i);
    float4 f1 = *(const float4*)(src + i + 4);
    v8bf o;
    o[0] = (__bf16)f0.x; o[1] = (__bf16)f0.y; o[2] = (__bf16)f0.z; o[3] = (__bf16)f0.w;
    o[4] = (__bf16)f1.x; o[5] = (__bf16)f1.y; o[6] = (__bf16)f1.z; o[7] = (__bf16)f1.w;
    *(v8bf*)(dst + i) = o;
  } else {
    const int idx = blk - 2049;                 // [0,1024)
    const int t0 = (idx & 15) * 64, c0 = ((idx >> 4) & 15) * 64, b = idx >> 8;
    {
      int row = tid >> 2, coff = (tid & 3) * 16;
      const float* src = x + ((long)b * CC + c0 + row) * TT + t0 + coff;
#pragma unroll
      for (int s = 0; s < 4; s++) {
        float4 f = *(const float4*)(src + s * 4);
        T[row][coff + s * 4 + 0] = (__bf16)f.x;
        T[row][coff + s * 4 + 1] = (__bf16)f.y;
        T[row][coff + s * 4 + 2] = (__bf16)f.z;
        T[row][coff + s * 4 + 3] = (__bf16)f.w;
      }
    }
    __syncthreads();
    {
      int trow = tid >> 2, ccoff = (tid & 3) * 16;
      __bf16 vals[16];
#pragma unroll
      for (int i = 0; i < 16; i++) vals[i] = T[ccoff + i][trow];
      __bf16* dst = xT + ((long)b * TT + t0 + trow) * CC + c0 + ccoff;
      *(v8bf*)dst       = *(v8bf*)&vals[0];
      *(v8bf*)(dst + 8) = *(v8bf*)&vals[8];
    }
  }
}

// ------- MFMA GEMM: C[m][n] = sum_k A[m][k]*BT[n][k]  (K=1024 fixed) -------
// MODE 0 (kvq): k,q thirds written TRANSPOSED into kqT [b][t][2C] via LDS
//               (fuses the old transpose_kq kernel); v third natural -> kvqb.
// MODE 1 (out): f32 out = acc + S.
template <int MODE, int NB, int MB>
__global__ __launch_bounds__(256) void gemm_bt(
    const __bf16* __restrict__ A, const __bf16* __restrict__ BTfull,
    const float* __restrict__ Sfull, void* __restrict__ Ofull,
    __bf16* __restrict__ kqT_out,
    long strideBT, long strideOS)
{
  constexpr int TOT = NB * MB * BB;
  int flat = blockIdx.x + NB * (blockIdx.y + MB * blockIdx.z);
  int L = (flat & 7) * (TOT / 8) + (flat >> 3);
  const int n0 = (L % NB) * 128;
  const int m0 = ((L / NB) % MB) * 128;
  const int zb = L / (NB * MB);
  const __bf16* BT = BTfull + (long)zb * strideBT;
  __shared__ __align__(16) __bf16 As[128 * 32];
  __shared__ __align__(16) __bf16 Bs[128 * 32];
  const int tid = threadIdx.x;
  const int lane = tid & 63, wave = tid >> 6;
  const int wm = wave >> 1, wn = wave & 1;
  const int ln = lane & 15, q = lane >> 4;

  v4f acc[4][4];
#pragma unroll
  for (int i = 0; i < 4; i++)
#pragma unroll
    for (int j = 0; j < 4; j++) acc[i][j] = (v4f)(0.f);

  const int e0 = tid * 8;
  const int r0 = e0 >> 5, c0 = e0 & 31;
  const int e1 = (256 + tid) * 8;
  const int r1 = e1 >> 5, c1 = e1 & 31;
  const __bf16* ga0 = A  + (long)(m0 + r0) * CC + c0;
  const __bf16* ga1 = A  + (long)(m0 + r1) * CC + c1;
  const __bf16* gb0 = BT + (long)(n0 + r0) * CC + c0;
  const __bf16* gb1 = BT + (long)(n0 + r1) * CC + c1;
  __bf16* lA0 = &As[wave * 512];
  __bf16* lA1 = &As[2048 + wave * 512];
  __bf16* lB0 = &Bs[wave * 512];
  __bf16* lB1 = &Bs[2048 + wave * 512];

  for (int k0 = 0; k0 < CC; k0 += 32) {
    async16(ga0 + k0, lA0);
    async16(ga1 + k0, lA1);
    async16(gb0 + k0, lB0);
    async16(gb1 + k0, lB1);
    __syncthreads();
    v8bf af[4], bfr[4];
#pragma unroll
    for (int mi = 0; mi < 4; mi++)
      af[mi] = *(v8bf*)&As[(wm * 64 + mi * 16 + ln) * 32 + q * 8];
#pragma unroll
    for (int ni = 0; ni < 4; ni++)
      bfr[ni] = *(v8bf*)&Bs[(wn * 64 + ni * 16 + ln) * 32 + q * 8];
#pragma unroll
    for (int mi = 0; mi < 4; mi++)
#pragma unroll
      for (int ni = 0; ni < 4; ni++)
        acc[mi][ni] = __builtin_amdgcn_mfma_f32_16x16x32_bf16(af[mi], bfr[ni], acc[mi][ni], 0, 0, 0);
    __syncthreads();
  }

  if constexpr (MODE == 0) {
    const int mb = m0 >> 7;                    // 0..7 k | 8..15 v | 16..23 q
    if (mb >= 8 && mb < 16) {
      // v third: natural bf16 store into kvqb rows [1024,2048)
#pragma unroll
      for (int mi = 0; mi < 4; mi++)
#pragma unroll
        for (int ni = 0; ni < 4; ni++)
#pragma unroll
          for (int r = 0; r < 4; r++) {
            int row = m0 + wm * 64 + mi * 16 + q * 4 + r;
            int col = n0 + wn * 64 + ni * 16 + ln;
            ((__bf16*)Ofull)[(long)zb * strideOS + (long)row * TT + col] = (__bf16)acc[mi][ni][r];
          }
    } else {
      // k/q thirds: transposed store kqT[t = n][c], c = m (k) or m-1024 (q).
      // Two phases by wm-half through a 128x72 LDS tile.
      __shared__ __align__(16) __bf16 Tt[128][72];
      const int cbase = (mb < 8) ? m0 : (m0 - 1024);
      __bf16* dstb = kqT_out + (long)zb * TT * (2 * CC);
#pragma unroll
      for (int ph = 0; ph < 2; ph++) {
        if (wm == ph) {
#pragma unroll
          for (int mi = 0; mi < 4; mi++)
#pragma unroll
            for (int ni = 0; ni < 4; ni++) {
              v4bf pb;
#pragma unroll
              for (int r = 0; r < 4; r++) pb[r] = (__bf16)acc[mi][ni][r];
              *(v4bf*)&Tt[wn * 64 + ni * 16 + ln][mi * 16 + q * 4] = pb;
            }
        }
        __syncthreads();
        {
          int row = tid & 127, half = tid >> 7;     // 64B per thread, coalesced
          v8bf x0 = *(v8bf*)&Tt[row][half * 32];
          v8bf x1 = *(v8bf*)&Tt[row][half * 32 + 8];
          v8bf x2 = *(v8bf*)&Tt[row][half * 32 + 16];
          v8bf x3 = *(v8bf*)&Tt[row][half * 32 + 24];
          __bf16* d = dstb + (long)(n0 + row) * (2 * CC) + cbase + ph * 64 + half * 32;
          *(v8bf*)(d)      = x0;
          *(v8bf*)(d + 8)  = x1;
          *(v8bf*)(d + 16) = x2;
          *(v8bf*)(d + 24) = x3;
        }
        __syncthreads();
      }
    }
  } else {
#pragma unroll
    for (int mi = 0; mi < 4; mi++)
#pragma unroll
      for (int ni = 0; ni < 4; ni++)
#pragma unroll
        for (int r = 0; r < 4; r++) {
          int row = m0 + wm * 64 + mi * 16 + q * 4 + r;
          int col = n0 + wn * 64 + ni * 16 + ln;
          long off = (long)zb * strideOS + (long)row * TT + col;
          ((float*)Ofull)[off] = acc[mi][ni][r] + Sfull[off];
        }
  }
}

// ------- stats: per (z, i-chunk 64, j) partial sumexp of logits ------------
__global__ __launch_bounds__(256) void attn_stats(
    const __bf16* __restrict__ kqT, const float* __restrict__ maskf,
    float* __restrict__ psum)
{
  int L = blockIdx.x + 8 * (blockIdx.y + 8 * blockIdx.z);
  L = (L & 7) * 512 + (L >> 3);                  // XCD chunk (4096 = 8*512)
  const int jx = L & 7, iy = (L >> 3) & 7, z = L >> 6;
  const int h = z >> 2, b = z & 3;
  const int i0 = iy * 128, j0 = jx * 128;
  const __bf16* kbase = kqT + (long)b * TT * (2 * CC);
  const int tid = threadIdx.x;
  const int lane = tid & 63, wave = tid >> 6;
  const int wi = wave >> 1, wj = wave & 1;
  const int ln = lane & 15, q = lane >> 4;

  v8bf ak[4][2], bq[4][2];
#pragma unroll
  for (int mi = 0; mi < 4; mi++) {
    const __bf16* ar = kbase + (long)(i0 + wi * 64 + mi * 16 + ln) * (2 * CC) + h * DD;
    ak[mi][0] = *(const v8bf*)(ar + q * 8);
    ak[mi][1] = *(const v8bf*)(ar + 32 + q * 8);
  }
#pragma unroll
  for (int ni = 0; ni < 4; ni++) {
    const __bf16* br = kbase + (long)(j0 + wj * 64 + ni * 16 + ln) * (2 * CC) + CC + h * DD;
    bq[ni][0] = *(const v8bf*)(br + q * 8);
    bq[ni][1] = *(const v8bf*)(br + 32 + q * 8);
  }

  v4f acc[4][4];
  __builtin_amdgcn_s_setprio(1);
#pragma unroll
  for (int mi = 0; mi < 4; mi++)
#pragma unroll
    for (int ni = 0; ni < 4; ni++) {
      v4f a = (v4f)(0.f);
      a = __builtin_amdgcn_mfma_f32_16x16x32_bf16(ak[mi][0], bq[ni][0], a, 0, 0, 0);
      a = __builtin_amdgcn_mfma_f32_16x16x32_bf16(ak[mi][1], bq[ni][1], a, 0, 0, 0);
      acc[mi][ni] = a;
    }
  __builtin_amdgcn_s_setprio(0);

  float kmv[4][4];
#pragma unroll
  for (int mi = 0; mi < 4; mi++)
#pragma unroll
    for (int r = 0; r < 4; r++)
      kmv[mi][r] = maskf[b * TT + i0 + wi * 64 + mi * 16 + q * 4 + r];

#pragma unroll
  for (int ni = 0; ni < 4; ni++) {
    float s = 0.f;
#pragma unroll
    for (int mi = 0; mi < 4; mi++)
#pragma unroll
      for (int r = 0; r < 4; r++) {
        float e = (kmv[mi][r] != 0.f) ? 0.f : __expf(acc[mi][ni][r] * 0.125f);
        s += e;
      }
    s += __shfl_xor(s, 16, 64);
    s += __shfl_xor(s, 32, 64);
    if (q == 0) {
      long so = ((long)z * 16 + (i0 >> 6) + wi) * TT + j0 + wj * 64 + ni * 16 + ln;
      psum[so] = s;
    }
  }
}

// ------- recompute logits, p=exp(l)*qz/S -> att; o^T = p^T v^T -------------
// __launch_bounds__(256,4): force VGPR<=128 so all 1024 blocks fit in ONE
// round (4 blocks/CU); at 144 VGPR it was 3/CU -> 768+256 two-round tail.
__global__ __launch_bounds__(256, 4) void gemm_pv(
    const __bf16* __restrict__ kqT, const __bf16* __restrict__ kvqb,
    const float* __restrict__ psum, const float* __restrict__ maskf,
    const unsigned int* __restrict__ kmb,
    float* __restrict__ att, __bf16* __restrict__ oT)
{
  int L = blockIdx.x + 16 * blockIdx.y;
  L = (L & 7) * 128 + (L >> 3);                 // XCD chunk (1024 = 8*128)
  const int z = L >> 4, jb = L & 15;
  const int h = z >> 2, b = z & 3;
  const int j0 = jb * 64;
  __shared__ __align__(16) char smem[37376];
  float* stl = (float*)smem;                    // [64] f32 @0
  unsigned int* kmw = (unsigned int*)(smem + 256);  // [32] u32 @256
  const int tid = threadIdx.x;
  const int lane = tid & 63, wave = tid >> 6;
  const int ln = lane & 15, q = lane >> 4;
  __bf16 (*Pt)[72] = (__bf16(*)[72])(smem + 512 + wave * 9216); // per-wave 64x72

  const __bf16* kbase = kqT + (long)b * TT * (2 * CC);
  const __bf16* vbase = kvqb + (long)(b * 3 * CC + CC + h * DD) * TT;

  if (tid < 64) {
    float S = 0.f;
#pragma unroll
    for (int t = 0; t < 16; t++) S += psum[((long)z * 16 + t) * TT + j0 + tid];
    stl[tid] = (maskf[b * TT + j0 + tid] != 0.f) ? 0.f : 1.f / S;
  }
  if (tid < 32) kmw[tid] = kmb[b * 32 + tid];
  __syncthreads();

  v8bf bq[4][2];
#pragma unroll
  for (int ni = 0; ni < 4; ni++) {
    const __bf16* qr = kbase + (long)(j0 + ni * 16 + ln) * (2 * CC) + CC + h * DD;
    bq[ni][0] = *(const v8bf*)(qr + q * 8);
    bq[ni][1] = *(const v8bf*)(qr + 32 + q * 8);
  }
  float stq[4];
#pragma unroll
  for (int ni = 0; ni < 4; ni++) stq[ni] = stl[ni * 16 + ln];

  v4f acc[4][4];
#pragma unroll
  for (int i = 0; i < 4; i++)
#pragma unroll
    for (int j = 0; j < 4; j++) acc[i][j] = (v4f)(0.f);

  for (int it = 0; it < 4; it++) {
    const int ibase = wave * 256 + it * 64;
#pragma unroll
    for (int mi = 0; mi < 4; mi++) {
      const __bf16* arow = kbase + (long)(ibase + mi * 16 + ln) * (2 * CC) + h * DD;
      v8bf ak0 = *(const v8bf*)(arow + q * 8);
      v8bf ak1 = *(const v8bf*)(arow + 32 + q * 8);
#pragma unroll
      for (int ni = 0; ni < 4; ni++) {
        v4f l4 = (v4f)(0.f);
        l4 = __builtin_amdgcn_mfma_f32_16x16x32_bf16(ak0, bq[ni][0], l4, 0, 0, 0);
        l4 = __builtin_amdgcn_mfma_f32_16x16x32_bf16(ak1, bq[ni][1], l4, 0, 0, 0);
        v4bf pb;
#pragma unroll
        for (int r = 0; r < 4; r++) {
          int i_loc = mi * 16 + q * 4 + r;
          int i_glob = ibase + i_loc;
          unsigned int mbit = (kmw[i_glob >> 5] >> (i_glob & 31)) & 1u;
          float p = mbit ? 0.f : __expf(l4[r] * 0.125f) * stq[ni];
          att[((long)z << 20) + (long)i_glob * TT + j0 + ni * 16 + ln] = p;
          pb[r] = (__bf16)p;
        }
        *(v4bf*)&Pt[ni * 16 + ln][mi * 16 + q * 4] = pb;
      }
    }
    v8bf ap[4][2], bv[4][2];
#pragma unroll
    for (int ji = 0; ji < 4; ji++)
#pragma unroll
      for (int ki = 0; ki < 2; ki++)
        ap[ji][ki] = *(v8bf*)&Pt[ji * 16 + ln][ki * 32 + q * 8];
#pragma unroll
    for (int di = 0; di < 4; di++)
#pragma unroll
      for (int ki = 0; ki < 2; ki++)
        bv[di][ki] = *(const v8bf*)(vbase + (long)(di * 16 + ln) * TT + ibase + ki * 32 + q * 8);
    __builtin_amdgcn_s_setprio(1);
#pragma unroll
    for (int ji = 0; ji < 4; ji++)
#pragma unroll
      for (int di = 0; di < 4; di++) {
        acc[ji][di] = __builtin_amdgcn_mfma_f32_16x16x32_bf16(ap[ji][0], bv[di][0], acc[ji][di], 0, 0, 0);
        acc[ji][di] = __builtin_amdgcn_mfma_f32_16x16x32_bf16(ap[ji][1], bv[di][1], acc[ji][di], 0, 0, 0);
      }
    __builtin_amdgcn_s_setprio(0);
  }

  float (*red0)[68] = (float(*)[68])(smem + 512);
  float (*red1)[68] = (float(*)[68])(smem + 512 + 17408);
  __syncthreads();
  if ((wave & 1) == 0) {
    float (*red)[68] = (wave == 0) ? red0 : red1;
#pragma unroll
    for (int ji = 0; ji < 4; ji++)
#pragma unroll
      for (int di = 0; di < 4; di++)
#pragma unroll
        for (int r = 0; r < 4; r++)
          red[ji * 16 + q * 4 + r][di * 16 + ln] = acc[ji][di][r];
  }
  __syncthreads();
  if ((wave & 1) == 1) {
    float (*red)[68] = (wave == 1) ? red0 : red1;
#pragma unroll
    for (int ji = 0; ji < 4; ji++)
#pragma unroll
      for (int di = 0; di < 4; di++)
#pragma unroll
        for (int r = 0; r < 4; r++)
          red[ji * 16 + q * 4 + r][di * 16 + ln] += acc[ji][di][r];
  }
  __syncthreads();
  {
    int row = tid >> 2, c0 = (tid & 3) * 16;
    __bf16 ob[16];
#pragma unroll
    for (int i = 0; i < 16; i++) ob[i] = (__bf16)(red0[row][c0 + i] + red1[row][c0 + i]);
    __bf16* dst = oT + ((long)b * TT + j0 + row) * CC + h * DD + c0;
    *(v8bf*)dst       = *(v8bf*)&ob[0];
    *(v8bf*)(dst + 8) = *(v8bf*)&ob[8];
  }
}

extern "C" void kernel_launch(void* const* d_in, const int* in_sizes, int n_in,
                              void* d_out, int out_size, void* d_ws, size_t ws_size,
                              hipStream_t stream) {
  const float* x     = (const float*)d_in[0];
  const void*  mask  = d_in[1];
  const float* w_kvq = (const float*)d_in[2];
  const float* w_out = (const float*)d_in[3];

  float* out = (float*)d_out;                     // [BB, CC, TT]
  float* att = out + (long)BB * CC * TT;          // [HH*BB, TT, TT]

  char* wsb = (char*)d_ws;
  float*   maskf = (float*)(wsb + 0);             // 16 KB
  __bf16*  wkb   = (__bf16*)(wsb + 16384);        // 6 MB
  __bf16*  wob   = (__bf16*)(wsb + 6307840);      // 2 MB
  __bf16*  xT    = (__bf16*)(wsb + 8404992);      // 8 MB   (region R)
  __bf16*  kqT   = (__bf16*)(wsb + 8404992);      // 16 MB  (region R, xT dead after kvq gemm)
  __bf16*  kvqb  = (__bf16*)(wsb + 25182208);     // 24 MB  (only v third written/read)
  __bf16*  oT    = (__bf16*)(wsb + 50348032);     // 8 MB
  float*   psum  = (float*)(wsb + 58736640);      // 4 MB, ends 62930944
  unsigned int* kmb = (unsigned int*)(wsb + 62930944); // 512 B (within proven 67.6MB)

  prep<<<3073, 256, 0, stream>>>(mask, maskf, kmb, w_kvq, w_out, wkb, wob, x, xT);
  // kvq gemm; k,q written transposed into kqT (xT still live while reading --
  // kqT writes land at [t][2C] in the same region only AFTER each tile's
  // B-reads of that k-range are done within the block... NOTE: xT and kqT
  // alias region R. Block (m0,n0) reads xT rows n0..n0+127 (all K) and writes
  // kqT rows n0..n0+127. Writes happen only in the epilogue, after ALL xT
  // reads by THIS block. Other blocks with different n0 never touch these
  // rows. Blocks sharing n0 (different m0) read xT rows n0.. concurrently
  // with another block's epilogue write to the same region-R rows? xT row t
  // occupies bytes [t*2048, t*2048+2048); kqT row t occupies [t*4096, ...).
  // DIFFERENT byte ranges -> row t of kqT overlaps rows 2t,2t+1 of xT!
  // Hazard: block A (n0=0) epilogue-writes kqT rows 0..127 = xT rows 0..255
  // while block B (n0=128, same zb) still reads xT rows 128..255. RACE.
  // -> kqT moved to its own region (see below), no aliasing.
  gemm_bt<0, 8, 24><<<dim3(8, 24, BB), 256, 0, stream>>>(
      wkb, xT, nullptr, kvqb, (__bf16*)(wsb + 67125248) /*kqT2, 16MB @64MB*/,
      (long)CC * TT, (long)3 * CC * TT);
  attn_stats<<<dim3(8, 8, HH * BB), 256, 0, stream>>>(
      (const __bf16*)(wsb + 67125248), maskf, psum);
  gemm_pv<<<dim3(16, HH * BB), 256, 0, stream>>>(
      (const __bf16*)(wsb + 67125248), kvqb, psum, maskf, kmb, att, oT);
  // out = x + w_out . o
  gemm_bt<1, 8, 8><<<dim3(8, 8, BB), 256, 0, stream>>>(
      wob, oT, x, out, nullptr, (long)CC * TT, (long)CC * TT);
}

// Round 6
// 453.192 us; speedup vs baseline: 3.0516x; 1.3400x over previous
//
#include <hip/hip_runtime.h>

#define BB 4
#define CC 1024
#define TT 1024
#define HH 16
#define DD 64

typedef __bf16 v8bf __attribute__((ext_vector_type(8)));
typedef __bf16 v4bf __attribute__((ext_vector_type(4)));
typedef float  v4f  __attribute__((ext_vector_type(4)));

// async global->LDS, 16B per lane. LDS dest must be wave-uniform base (HW writes
// base + lane*16); global src is per-lane.
__device__ __forceinline__ void async16(const __bf16* g, __bf16* l) {
  __builtin_amdgcn_global_load_lds(
      (const __attribute__((address_space(1))) void*)g,
      (__attribute__((address_space(3))) void*)l, 16, 0, 0);
}

// ---- prep: mask detection+expand+bitpack | weight casts | transpose_x ------
__global__ __launch_bounds__(256) void prep(
    const void* mraw, float* __restrict__ maskf, unsigned int* __restrict__ kmb,
    const float* __restrict__ w_kvq, const float* __restrict__ w_out,
    __bf16* __restrict__ wkb, __bf16* __restrict__ wob,
    const float* __restrict__ x, __bf16* __restrict__ xT)
{
  const int blk = blockIdx.x;
  const int tid = threadIdx.x;
  __shared__ int flagA, flagB;
  __shared__ __bf16 T[64][72];

  if (blk == 0) {
    if (tid == 0) { flagA = 0; flagB = 0; }
    __syncthreads();
    const unsigned char* mb = (const unsigned char*)mraw;
    const int n = BB * TT;
    int a = 0, bfl = 0;
    for (int i = tid; i < n; i += 256) {
      if (mb[i]) { if ((i & 3) == 0) a = 1; else bfl = 1; }
    }
    if (a)   atomicOr(&flagA, 1);
    if (bfl) atomicOr(&flagB, 1);
    __syncthreads();
    int layout;                         // 0=int32, 1=float32, 2=uint8
    if (flagA && !flagB)      layout = 0;
    else if (!flagA && flagB) layout = 1;
    else                      layout = 2;
    const int lane = tid & 63, wave = tid >> 6;
    for (int it = 0; it < 16; it++) {
      int i = it * 256 + tid;
      float m;
      if (layout == 0)      m = (((const int*)mraw)[i]   != 0)   ? 1.f : 0.f;
      else if (layout == 1) m = (((const float*)mraw)[i] != 0.f) ? 1.f : 0.f;
      else                  m = (mb[i] != 0)                     ? 1.f : 0.f;
      maskf[i] = m;
      unsigned long long bal = __ballot(m != 0.f);
      if (lane == 0) {
        int base = (it * 256 + wave * 64) >> 5;
        kmb[base]     = (unsigned int)bal;
        kmb[base + 1] = (unsigned int)(bal >> 32);
      }
    }
  } else if (blk <= 2048) {
    const int cb = blk - 1;
    const float* src; __bf16* dst; int base;
    if (cb < 1536) { src = w_kvq; dst = wkb; base = cb * 2048; }
    else           { src = w_out; dst = wob; base = (cb - 1536) * 2048; }
    int i = base + tid * 8;
    float4 f0 = *(const float4*)(src + i);
    float4 f1 = *(const float4*)(src + i + 4);
    v8bf o;
    o[0] = (__bf16)f0.x; o[1] = (__bf16)f0.y; o[2] = (__bf16)f0.z; o[3] = (__bf16)f0.w;
    o[4] = (__bf16)f1.x; o[5] = (__bf16)f1.y; o[6] = (__bf16)f1.z; o[7] = (__bf16)f1.w;
    *(v8bf*)(dst + i) = o;
  } else {
    const int idx = blk - 2049;                 // [0,1024)
    const int t0 = (idx & 15) * 64, c0 = ((idx >> 4) & 15) * 64, b = idx >> 8;
    {
      int row = tid >> 2, coff = (tid & 3) * 16;
      const float* src = x + ((long)b * CC + c0 + row) * TT + t0 + coff;
#pragma unroll
      for (int s = 0; s < 4; s++) {
        float4 f = *(const float4*)(src + s * 4);
        T[row][coff + s * 4 + 0] = (__bf16)f.x;
        T[row][coff + s * 4 + 1] = (__bf16)f.y;
        T[row][coff + s * 4 + 2] = (__bf16)f.z;
        T[row][coff + s * 4 + 3] = (__bf16)f.w;
      }
    }
    __syncthreads();
    {
      int trow = tid >> 2, ccoff = (tid & 3) * 16;
      __bf16 vals[16];
#pragma unroll
      for (int i = 0; i < 16; i++) vals[i] = T[ccoff + i][trow];
      __bf16* dst = xT + ((long)b * TT + t0 + trow) * CC + c0 + ccoff;
      *(v8bf*)dst       = *(v8bf*)&vals[0];
      *(v8bf*)(dst + 8) = *(v8bf*)&vals[8];
    }
  }
}

// ------- MFMA GEMM: C[m][n] = sum_k A[m][k]*BT[n][k]  (K=1024 fixed) -------
// MODE 0 (kvq): k,q thirds written TRANSPOSED into kqT [b][t][2C] via LDS
//               (fused transpose); v third natural -> kvqb.
// MODE 1 (out): f32 out = acc + S.
template <int MODE, int NB, int MB>
__global__ __launch_bounds__(256) void gemm_bt(
    const __bf16* __restrict__ A, const __bf16* __restrict__ BTfull,
    const float* __restrict__ Sfull, void* __restrict__ Ofull,
    __bf16* __restrict__ kqT_out,
    long strideBT, long strideOS)
{
  constexpr int TOT = NB * MB * BB;
  int flat = blockIdx.x + NB * (blockIdx.y + MB * blockIdx.z);
  int L = (flat & 7) * (TOT / 8) + (flat >> 3);
  const int n0 = (L % NB) * 128;
  const int m0 = ((L / NB) % MB) * 128;
  const int zb = L / (NB * MB);
  const __bf16* BT = BTfull + (long)zb * strideBT;
  __shared__ __align__(16) __bf16 As[128 * 32];
  __shared__ __align__(16) __bf16 Bs[128 * 32];
  const int tid = threadIdx.x;
  const int lane = tid & 63, wave = tid >> 6;
  const int wm = wave >> 1, wn = wave & 1;
  const int ln = lane & 15, q = lane >> 4;

  v4f acc[4][4];
#pragma unroll
  for (int i = 0; i < 4; i++)
#pragma unroll
    for (int j = 0; j < 4; j++) acc[i][j] = (v4f)(0.f);

  const int e0 = tid * 8;
  const int r0 = e0 >> 5, c0 = e0 & 31;
  const int e1 = (256 + tid) * 8;
  const int r1 = e1 >> 5, c1 = e1 & 31;
  const __bf16* ga0 = A  + (long)(m0 + r0) * CC + c0;
  const __bf16* ga1 = A  + (long)(m0 + r1) * CC + c1;
  const __bf16* gb0 = BT + (long)(n0 + r0) * CC + c0;
  const __bf16* gb1 = BT + (long)(n0 + r1) * CC + c1;
  __bf16* lA0 = &As[wave * 512];
  __bf16* lA1 = &As[2048 + wave * 512];
  __bf16* lB0 = &Bs[wave * 512];
  __bf16* lB1 = &Bs[2048 + wave * 512];

  for (int k0 = 0; k0 < CC; k0 += 32) {
    async16(ga0 + k0, lA0);
    async16(ga1 + k0, lA1);
    async16(gb0 + k0, lB0);
    async16(gb1 + k0, lB1);
    __syncthreads();
    v8bf af[4], bfr[4];
#pragma unroll
    for (int mi = 0; mi < 4; mi++)
      af[mi] = *(v8bf*)&As[(wm * 64 + mi * 16 + ln) * 32 + q * 8];
#pragma unroll
    for (int ni = 0; ni < 4; ni++)
      bfr[ni] = *(v8bf*)&Bs[(wn * 64 + ni * 16 + ln) * 32 + q * 8];
#pragma unroll
    for (int mi = 0; mi < 4; mi++)
#pragma unroll
      for (int ni = 0; ni < 4; ni++)
        acc[mi][ni] = __builtin_amdgcn_mfma_f32_16x16x32_bf16(af[mi], bfr[ni], acc[mi][ni], 0, 0, 0);
    __syncthreads();
  }

  if constexpr (MODE == 0) {
    const int mb = m0 >> 7;                    // 0..7 k | 8..15 v | 16..23 q
    if (mb >= 8 && mb < 16) {
      // v third: natural bf16 store into kvqb rows [1024,2048)
#pragma unroll
      for (int mi = 0; mi < 4; mi++)
#pragma unroll
        for (int ni = 0; ni < 4; ni++)
#pragma unroll
          for (int r = 0; r < 4; r++) {
            int row = m0 + wm * 64 + mi * 16 + q * 4 + r;
            int col = n0 + wn * 64 + ni * 16 + ln;
            ((__bf16*)Ofull)[(long)zb * strideOS + (long)row * TT + col] = (__bf16)acc[mi][ni][r];
          }
    } else {
      // k/q thirds: transposed store kqT[t = n][c]; two phases through LDS.
      __shared__ __align__(16) __bf16 Tt[128][72];
      const int cbase = (mb < 8) ? m0 : (m0 - 1024);
      __bf16* dstb = kqT_out + (long)zb * TT * (2 * CC);
#pragma unroll
      for (int ph = 0; ph < 2; ph++) {
        if (wm == ph) {
#pragma unroll
          for (int mi = 0; mi < 4; mi++)
#pragma unroll
            for (int ni = 0; ni < 4; ni++) {
              v4bf pb;
#pragma unroll
              for (int r = 0; r < 4; r++) pb[r] = (__bf16)acc[mi][ni][r];
              *(v4bf*)&Tt[wn * 64 + ni * 16 + ln][mi * 16 + q * 4] = pb;
            }
        }
        __syncthreads();
        {
          int row = tid & 127, half = tid >> 7;     // 64B per thread, coalesced
          v8bf x0 = *(v8bf*)&Tt[row][half * 32];
          v8bf x1 = *(v8bf*)&Tt[row][half * 32 + 8];
          v8bf x2 = *(v8bf*)&Tt[row][half * 32 + 16];
          v8bf x3 = *(v8bf*)&Tt[row][half * 32 + 24];
          __bf16* d = dstb + (long)(n0 + row) * (2 * CC) + cbase + ph * 64 + half * 32;
          *(v8bf*)(d)      = x0;
          *(v8bf*)(d + 8)  = x1;
          *(v8bf*)(d + 16) = x2;
          *(v8bf*)(d + 24) = x3;
        }
        __syncthreads();
      }
    }
  } else {
#pragma unroll
    for (int mi = 0; mi < 4; mi++)
#pragma unroll
      for (int ni = 0; ni < 4; ni++)
#pragma unroll
        for (int r = 0; r < 4; r++) {
          int row = m0 + wm * 64 + mi * 16 + q * 4 + r;
          int col = n0 + wn * 64 + ni * 16 + ln;
          long off = (long)zb * strideOS + (long)row * TT + col;
          ((float*)Ofull)[off] = acc[mi][ni][r] + Sfull[off];
        }
  }
}

// ------- fused softmax+PV: phase1 computes S per column (block covers ALL i),
// phase2 recomputes logits, p=exp(l)*qz/S -> att, o^T = p^T v^T.
// Plain __launch_bounds__(256): R5's (256,4) clamp forced VGPR=64 and spilled
// (FETCH 245MB / +177MB writes of scratch). 144-160 VGPR / 3 blocks/CU is the
// measured-better operating point (R4: 67us/pass).
__global__ __launch_bounds__(256) void gemm_pv(
    const __bf16* __restrict__ kqT, const __bf16* __restrict__ kvqb,
    const float* __restrict__ maskf, const unsigned int* __restrict__ kmb,
    float* __restrict__ att, __bf16* __restrict__ oT)
{
  int L = blockIdx.x + 16 * blockIdx.y;
  L = (L & 7) * 128 + (L >> 3);                 // XCD chunk (1024 = 8*128)
  const int z = L >> 4, jb = L & 15;
  const int h = z >> 2, b = z & 3;
  const int j0 = jb * 64;
  __shared__ __align__(16) char smem[38400];
  float* stl = (float*)smem;                        // [64] f32  @0
  unsigned int* kmw = (unsigned int*)(smem + 256);  // [32] u32  @256
  float (*sred)[64] = (float(*)[64])(smem + 512);   // [4][64]   @512..1536
  const int tid = threadIdx.x;
  const int lane = tid & 63, wave = tid >> 6;
  const int ln = lane & 15, q = lane >> 4;
  __bf16 (*Pt)[72] = (__bf16(*)[72])(smem + 1536 + wave * 9216); // per-wave 64x72

  const __bf16* kbase = kqT + (long)b * TT * (2 * CC);
  const __bf16* vbase = kvqb + (long)(b * 3 * CC + CC + h * DD) * TT;

  if (tid < 32) kmw[tid] = kmb[b * 32 + tid];
  __syncthreads();

  v8bf bq[4][2];
#pragma unroll
  for (int ni = 0; ni < 4; ni++) {
    const __bf16* qr = kbase + (long)(j0 + ni * 16 + ln) * (2 * CC) + CC + h * DD;
    bq[ni][0] = *(const v8bf*)(qr + q * 8);
    bq[ni][1] = *(const v8bf*)(qr + 32 + q * 8);
  }

  // ---- phase 1: S[j] = sum_i e(i,j) over this block's full i-range --------
  float s[4] = {0.f, 0.f, 0.f, 0.f};
  for (int it = 0; it < 4; it++) {
    const int ibase = wave * 256 + it * 64;
#pragma unroll
    for (int mi = 0; mi < 4; mi++) {
      const __bf16* arow = kbase + (long)(ibase + mi * 16 + ln) * (2 * CC) + h * DD;
      v8bf ak0 = *(const v8bf*)(arow + q * 8);
      v8bf ak1 = *(const v8bf*)(arow + 32 + q * 8);
#pragma unroll
      for (int ni = 0; ni < 4; ni++) {
        v4f l4 = (v4f)(0.f);
        l4 = __builtin_amdgcn_mfma_f32_16x16x32_bf16(ak0, bq[ni][0], l4, 0, 0, 0);
        l4 = __builtin_amdgcn_mfma_f32_16x16x32_bf16(ak1, bq[ni][1], l4, 0, 0, 0);
#pragma unroll
        for (int r = 0; r < 4; r++) {
          int i_glob = ibase + mi * 16 + q * 4 + r;
          unsigned int mbit = (kmw[i_glob >> 5] >> (i_glob & 31)) & 1u;
          s[ni] += mbit ? 0.f : __expf(l4[r] * 0.125f);
        }
      }
    }
  }
#pragma unroll
  for (int ni = 0; ni < 4; ni++) {
    s[ni] += __shfl_xor(s[ni], 16, 64);
    s[ni] += __shfl_xor(s[ni], 32, 64);
    if (q == 0) sred[wave][ni * 16 + ln] = s[ni];
  }
  __syncthreads();
  if (tid < 64) {
    float S = sred[0][tid] + sred[1][tid] + sred[2][tid] + sred[3][tid];
    stl[tid] = (maskf[b * TT + j0 + tid] != 0.f) ? 0.f : 1.f / S;
  }
  __syncthreads();
  float stq[4];
#pragma unroll
  for (int ni = 0; ni < 4; ni++) stq[ni] = stl[ni * 16 + ln];

  // ---- phase 2: recompute logits, att store, PV ---------------------------
  v4f acc[4][4];
#pragma unroll
  for (int i = 0; i < 4; i++)
#pragma unroll
    for (int j = 0; j < 4; j++) acc[i][j] = (v4f)(0.f);

  for (int it = 0; it < 4; it++) {
    const int ibase = wave * 256 + it * 64;
#pragma unroll
    for (int mi = 0; mi < 4; mi++) {
      const __bf16* arow = kbase + (long)(ibase + mi * 16 + ln) * (2 * CC) + h * DD;
      v8bf ak0 = *(const v8bf*)(arow + q * 8);
      v8bf ak1 = *(const v8bf*)(arow + 32 + q * 8);
#pragma unroll
      for (int ni = 0; ni < 4; ni++) {
        v4f l4 = (v4f)(0.f);
        l4 = __builtin_amdgcn_mfma_f32_16x16x32_bf16(ak0, bq[ni][0], l4, 0, 0, 0);
        l4 = __builtin_amdgcn_mfma_f32_16x16x32_bf16(ak1, bq[ni][1], l4, 0, 0, 0);
        v4bf pb;
#pragma unroll
        for (int r = 0; r < 4; r++) {
          int i_loc = mi * 16 + q * 4 + r;
          int i_glob = ibase + i_loc;
          unsigned int mbit = (kmw[i_glob >> 5] >> (i_glob & 31)) & 1u;
          float p = mbit ? 0.f : __expf(l4[r] * 0.125f) * stq[ni];
          att[((long)z << 20) + (long)i_glob * TT + j0 + ni * 16 + ln] = p;
          pb[r] = (__bf16)p;
        }
        *(v4bf*)&Pt[ni * 16 + ln][mi * 16 + q * 4] = pb;
      }
    }
    v8bf ap[4][2], bv[4][2];
#pragma unroll
    for (int ji = 0; ji < 4; ji++)
#pragma unroll
      for (int ki = 0; ki < 2; ki++)
        ap[ji][ki] = *(v8bf*)&Pt[ji * 16 + ln][ki * 32 + q * 8];
#pragma unroll
    for (int di = 0; di < 4; di++)
#pragma unroll
      for (int ki = 0; ki < 2; ki++)
        bv[di][ki] = *(const v8bf*)(vbase + (long)(di * 16 + ln) * TT + ibase + ki * 32 + q * 8);
    __builtin_amdgcn_s_setprio(1);
#pragma unroll
    for (int ji = 0; ji < 4; ji++)
#pragma unroll
      for (int di = 0; di < 4; di++) {
        acc[ji][di] = __builtin_amdgcn_mfma_f32_16x16x32_bf16(ap[ji][0], bv[di][0], acc[ji][di], 0, 0, 0);
        acc[ji][di] = __builtin_amdgcn_mfma_f32_16x16x32_bf16(ap[ji][1], bv[di][1], acc[ji][di], 0, 0, 0);
      }
    __builtin_amdgcn_s_setprio(0);
  }

  // cross-wave k-split reduction, 2-level tree; red overlays dead Pt area.
  float (*red0)[68] = (float(*)[68])(smem + 1536);
  float (*red1)[68] = (float(*)[68])(smem + 1536 + 17408);
  __syncthreads();
  if ((wave & 1) == 0) {
    float (*red)[68] = (wave == 0) ? red0 : red1;
#pragma unroll
    for (int ji = 0; ji < 4; ji++)
#pragma unroll
      for (int di = 0; di < 4; di++)
#pragma unroll
        for (int r = 0; r < 4; r++)
          red[ji * 16 + q * 4 + r][di * 16 + ln] = acc[ji][di][r];
  }
  __syncthreads();
  if ((wave & 1) == 1) {
    float (*red)[68] = (wave == 1) ? red0 : red1;
#pragma unroll
    for (int ji = 0; ji < 4; ji++)
#pragma unroll
      for (int di = 0; di < 4; di++)
#pragma unroll
        for (int r = 0; r < 4; r++)
          red[ji * 16 + q * 4 + r][di * 16 + ln] += acc[ji][di][r];
  }
  __syncthreads();
  {
    int row = tid >> 2, c0 = (tid & 3) * 16;
    __bf16 ob[16];
#pragma unroll
    for (int i = 0; i < 16; i++) ob[i] = (__bf16)(red0[row][c0 + i] + red1[row][c0 + i]);
    __bf16* dst = oT + ((long)b * TT + j0 + row) * CC + h * DD + c0;
    *(v8bf*)dst       = *(v8bf*)&ob[0];
    *(v8bf*)(dst + 8) = *(v8bf*)&ob[8];
  }
}

extern "C" void kernel_launch(void* const* d_in, const int* in_sizes, int n_in,
                              void* d_out, int out_size, void* d_ws, size_t ws_size,
                              hipStream_t stream) {
  const float* x     = (const float*)d_in[0];
  const void*  mask  = d_in[1];
  const float* w_kvq = (const float*)d_in[2];
  const float* w_out = (const float*)d_in[3];

  float* out = (float*)d_out;                     // [BB, CC, TT]
  float* att = out + (long)BB * CC * TT;          // [HH*BB, TT, TT]

  char* wsb = (char*)d_ws;
  float*   maskf = (float*)(wsb + 0);             // 16 KB
  __bf16*  wkb   = (__bf16*)(wsb + 16384);        // 6 MB
  __bf16*  wob   = (__bf16*)(wsb + 6307840);      // 2 MB
  __bf16*  xT    = (__bf16*)(wsb + 8404992);      // 8 MB
  __bf16*  kvqb  = (__bf16*)(wsb + 25182208);     // 24 MB (only v third used)
  __bf16*  oT    = (__bf16*)(wsb + 50348032);     // 8 MB
  unsigned int* kmb = (unsigned int*)(wsb + 62930944); // 512 B
  __bf16*  kqT   = (__bf16*)(wsb + 67125248);     // 16 MB (own region; no alias vs xT)

  prep<<<3073, 256, 0, stream>>>(mask, maskf, kmb, w_kvq, w_out, wkb, wob, x, xT);
  // kvq gemm; k,q thirds written transposed into kqT, v third into kvqb
  gemm_bt<0, 8, 24><<<dim3(8, 24, BB), 256, 0, stream>>>(
      wkb, xT, nullptr, kvqb, kqT, (long)CC * TT, (long)3 * CC * TT);
  // fused stats+softmax+PV (phase1 denominators in-block, phase2 att+PV)
  gemm_pv<<<dim3(16, HH * BB), 256, 0, stream>>>(kqT, kvqb, maskf, kmb, att, oT);
  // out = x + w_out . o
  gemm_bt<1, 8, 8><<<dim3(8, 8, BB), 256, 0, stream>>>(
      wob, oT, x, out, nullptr, (long)CC * TT, (long)CC * TT);
}